// Round 1
// baseline (3315.188 us; speedup 1.0000x reference)
//
#include <hip/hip_runtime.h>
#include <math.h>

#define Bn   16
#define Nn   4096
#define Cn   64
#define Dn   67      // 3 + 64
#define Mn   1024
#define Kn   32
#define OUTn 128
#define EPS  1e-5f

// ---------------------------------------------------------------------------
// FPS: one block per batch, 1024 threads, 4 points/thread in registers.
// Exactly one __syncthreads per step (parity-buffered wave partials).
// Matches reference: d0 = ||p - p0||^2; step: nxt = argmax(d) (first-max
// tie-break), d = min(d, ||p - p[nxt]||^2). Writes centroid coords directly.
// ---------------------------------------------------------------------------
__global__ __launch_bounds__(1024) void fps_kernel(
    const float* __restrict__ xyz, float* __restrict__ cent)
{
  __shared__ float pts[Nn * 3];     // 48 KB point cache
  __shared__ float pv[2][16];
  __shared__ int   pi[2][16];

  const int b = blockIdx.x;
  const int t = threadIdx.x;
  const float* src = xyz + (size_t)b * Nn * 3;

  for (int i = t; i < Nn * 3; i += 1024) pts[i] = src[i];
  __syncthreads();

  const float c0x = pts[0], c0y = pts[1], c0z = pts[2];

  float px[4], py[4], pz[4], d[4];
  float bv = -1.0f; int bi = 0;
#pragma unroll
  for (int j = 0; j < 4; ++j) {
    const int n = j * 1024 + t;
    px[j] = pts[n * 3 + 0];
    py[j] = pts[n * 3 + 1];
    pz[j] = pts[n * 3 + 2];
    const float dx = px[j] - c0x, dy = py[j] - c0y, dz = pz[j] - c0z;
    d[j] = (dx * dx + dy * dy) + dz * dz;
    if (d[j] > bv) { bv = d[j]; bi = n; }   // ascending n => first-max kept
  }

  if (t == 0) {
    float* o = cent + (size_t)b * Mn * 3;
    o[0] = c0x; o[1] = c0y; o[2] = c0z;
  }

  for (int m = 1; m < Mn; ++m) {
    // wave-level argmax butterfly (max value, tie -> lower index)
    float v = bv; int i0 = bi;
#pragma unroll
    for (int off = 1; off < 64; off <<= 1) {
      const float ov = __shfl_xor(v, off);
      const int   oi = __shfl_xor(i0, off);
      if (ov > v || (ov == v && oi < i0)) { v = ov; i0 = oi; }
    }
    const int par = m & 1;
    if ((t & 63) == 0) { pv[par][t >> 6] = v; pi[par][t >> 6] = i0; }
    __syncthreads();

    // every thread combines the 16 wave partials (broadcast LDS reads)
    float fv = pv[par][0]; int fi = pi[par][0];
#pragma unroll
    for (int q = 1; q < 16; ++q) {
      const float qv = pv[par][q]; const int qi = pi[par][q];
      if (qv > fv || (qv == fv && qi < fi)) { fv = qv; fi = qi; }
    }

    const float cx = pts[fi * 3 + 0];
    const float cy = pts[fi * 3 + 1];
    const float cz = pts[fi * 3 + 2];
    if (t == 0) {
      float* o = cent + ((size_t)b * Mn + m) * 3;
      o[0] = cx; o[1] = cy; o[2] = cz;
    }

    // fused distance update + local argmax rescan
    bv = -1.0f; bi = 0;
#pragma unroll
    for (int j = 0; j < 4; ++j) {
      const float dx = px[j] - cx, dy = py[j] - cy, dz = pz[j] - cz;
      const float nd = (dx * dx + dy * dy) + dz * dz;
      d[j] = fminf(d[j], nd);
      const int n = j * 1024 + t;
      if (d[j] > bv) { bv = d[j]; bi = n; }
    }
  }
}

// ---------------------------------------------------------------------------
// Fused KNN + gather + MLP(3 layers, 2 LayerNorm+ReLU) + max-pool.
// One block (256 threads) per centroid (b, m); 16 points per thread.
// KNN: 32 iterative argmin extractions, (value, lower-index) tie-break ->
// identical selected SET to stable top_k(-d2, 32). d2 uses the reference
// formula (cc + pp) - 2*dot in f32.
// ---------------------------------------------------------------------------
__global__ __launch_bounds__(256) void sa_kernel(
    const float* __restrict__ xyz, const float* __restrict__ feat,
    const float* __restrict__ W1, const float* __restrict__ b1,
    const float* __restrict__ g1, const float* __restrict__ be1,
    const float* __restrict__ W2, const float* __restrict__ b2,
    const float* __restrict__ g2, const float* __restrict__ be2,
    const float* __restrict__ Wout, const float* __restrict__ bout,
    const float* __restrict__ cent, float* __restrict__ out)
{
  __shared__ float Xs[Kn][68];      // 32 x 67 (+pad), rows 272B (16B aligned)
  __shared__ float Hs[Kn][64];      // hidden activations
  __shared__ int   sel[Kn];
  __shared__ float pvv[2][4];
  __shared__ int   pii[2][4];
  __shared__ float omax[2][OUTn];

  const int bm = blockIdx.x;
  const int b  = bm >> 10;
  const int m  = bm & 1023;
  const int t  = threadIdx.x;

  const float* P = xyz  + (size_t)b * Nn * 3;
  const float* F = feat + (size_t)b * Nn * Cn;

  const float cx = cent[((size_t)b * Mn + m) * 3 + 0];
  const float cy = cent[((size_t)b * Mn + m) * 3 + 1];
  const float cz = cent[((size_t)b * Mn + m) * 3 + 2];
  const float cc = (cx * cx + cy * cy) + cz * cz;

  // ---- distances (reference formula) ----
  float d2[16];
#pragma unroll
  for (int j = 0; j < 16; ++j) {
    const int n = j * 256 + t;
    const float x = P[n * 3 + 0], y = P[n * 3 + 1], z = P[n * 3 + 2];
    const float pp = (x * x + y * y) + z * z;
    const float dt = (cx * x + cy * y) + cz * z;
    d2[j] = (cc + pp) - 2.0f * dt;
  }

  // cached per-thread min candidate
  float bv = d2[0]; int bslot = 0;
#pragma unroll
  for (int j = 1; j < 16; ++j)
    if (d2[j] < bv) { bv = d2[j]; bslot = j; }
  int bidx = bslot * 256 + t;

  // ---- 32 argmin extractions ----
  for (int s = 0; s < Kn; ++s) {
    float v = bv; int i0 = bidx;
#pragma unroll
    for (int off = 1; off < 64; off <<= 1) {
      const float ov = __shfl_xor(v, off);
      const int   oi = __shfl_xor(i0, off);
      if (ov < v || (ov == v && oi < i0)) { v = ov; i0 = oi; }
    }
    const int par = s & 1;
    if ((t & 63) == 0) { pvv[par][t >> 6] = v; pii[par][t >> 6] = i0; }
    __syncthreads();

    float fv = pvv[par][0]; int fi = pii[par][0];
#pragma unroll
    for (int q = 1; q < 4; ++q) {
      const float qv = pvv[par][q]; const int qi = pii[par][q];
      if (qv < fv || (qv == fv && qi < fi)) { fv = qv; fi = qi; }
    }
    if (t == 0) sel[s] = fi;

    if ((fi & 255) == t) {          // owner masks + rescans its 16 (registers)
      const int slot = fi >> 8;
#pragma unroll
      for (int j = 0; j < 16; ++j)
        if (j == slot) d2[j] = INFINITY;
      bv = INFINITY; bslot = 0;
#pragma unroll
      for (int j = 0; j < 16; ++j)
        if (d2[j] < bv) { bv = d2[j]; bslot = j; }
      bidx = bslot * 256 + t;
    }
  }
  __syncthreads();

  // ---- gather X = [p - c | features] ----
  {
    const int r  = t >> 3;    // 0..31
    const int l8 = t & 7;     // 0..7
    const int n  = sel[r];
    if (l8 == 0) {
      Xs[r][0] = P[n * 3 + 0] - cx;
      Xs[r][1] = P[n * 3 + 1] - cy;
      Xs[r][2] = P[n * 3 + 2] - cz;
    }
#pragma unroll
    for (int q = 0; q < 8; ++q) {
      const int c = l8 * 8 + q;
      Xs[r][3 + c] = F[(size_t)n * Cn + c];
    }
  }
  __syncthreads();

  // ---- layer 1: Hs = Xs @ W1^T + b1  (K = 67) ----
  {
    const int c  = t & 63;
    const int rs = t >> 6;    // wave id -> rows rs*8 .. rs*8+7
    float acc[8];
#pragma unroll
    for (int i = 0; i < 8; ++i) acc[i] = b1[c];
    const float* w = W1 + c * Dn;
    for (int kc = 0; kc < 16; ++kc) {
      const float w0 = w[4 * kc + 0], w1v = w[4 * kc + 1];
      const float w2v = w[4 * kc + 2], w3v = w[4 * kc + 3];
#pragma unroll
      for (int i = 0; i < 8; ++i) {
        const float4 xv = *reinterpret_cast<const float4*>(&Xs[rs * 8 + i][4 * kc]);
        acc[i] = fmaf(xv.x, w0,  acc[i]);
        acc[i] = fmaf(xv.y, w1v, acc[i]);
        acc[i] = fmaf(xv.z, w2v, acc[i]);
        acc[i] = fmaf(xv.w, w3v, acc[i]);
      }
    }
    {
      const float wt0 = w[64], wt1 = w[65], wt2 = w[66];
#pragma unroll
      for (int i = 0; i < 8; ++i) {
        const int r = rs * 8 + i;
        acc[i] = fmaf(Xs[r][64], wt0, acc[i]);
        acc[i] = fmaf(Xs[r][65], wt1, acc[i]);
        acc[i] = fmaf(Xs[r][66], wt2, acc[i]);
      }
    }
#pragma unroll
    for (int i = 0; i < 8; ++i) Hs[rs * 8 + i][c] = acc[i];
  }
  __syncthreads();

  // ---- LN1 + ReLU (rows of 64; one wave per 8 rows, lane = column) ----
  {
    const int lane = t & 63;
    const int wv   = t >> 6;
    const float gv = g1[lane], bb = be1[lane];
#pragma unroll
    for (int rr = 0; rr < 8; ++rr) {
      const int r = wv * 8 + rr;
      const float x = Hs[r][lane];
      float s = x;
#pragma unroll
      for (int off = 1; off < 64; off <<= 1) s += __shfl_xor(s, off);
      const float mu = s * 0.015625f;
      const float dv = x - mu;
      float q = dv * dv;
#pragma unroll
      for (int off = 1; off < 64; off <<= 1) q += __shfl_xor(q, off);
      const float var = q * 0.015625f;
      const float y = dv * rsqrtf(var + EPS) * gv + bb;
      Hs[r][lane] = fmaxf(y, 0.0f);
    }
  }
  __syncthreads();

  // ---- layer 2: Xs[.][0..63] = Hs @ W2^T + b2  (K = 64) ----
  {
    const int c  = t & 63;
    const int rs = t >> 6;
    float acc[8];
#pragma unroll
    for (int i = 0; i < 8; ++i) acc[i] = b2[c];
    const float* w = W2 + c * 64;
    for (int kc = 0; kc < 16; ++kc) {
      const float w0 = w[4 * kc + 0], w1v = w[4 * kc + 1];
      const float w2v = w[4 * kc + 2], w3v = w[4 * kc + 3];
#pragma unroll
      for (int i = 0; i < 8; ++i) {
        const float4 xv = *reinterpret_cast<const float4*>(&Hs[rs * 8 + i][4 * kc]);
        acc[i] = fmaf(xv.x, w0,  acc[i]);
        acc[i] = fmaf(xv.y, w1v, acc[i]);
        acc[i] = fmaf(xv.z, w2v, acc[i]);
        acc[i] = fmaf(xv.w, w3v, acc[i]);
      }
    }
#pragma unroll
    for (int i = 0; i < 8; ++i) Xs[rs * 8 + i][c] = acc[i];
  }
  __syncthreads();

  // ---- LN2 + ReLU (on Xs, stride 68) ----
  {
    const int lane = t & 63;
    const int wv   = t >> 6;
    const float gv = g2[lane], bb = be2[lane];
#pragma unroll
    for (int rr = 0; rr < 8; ++rr) {
      const int r = wv * 8 + rr;
      const float x = Xs[r][lane];
      float s = x;
#pragma unroll
      for (int off = 1; off < 64; off <<= 1) s += __shfl_xor(s, off);
      const float mu = s * 0.015625f;
      const float dv = x - mu;
      float q = dv * dv;
#pragma unroll
      for (int off = 1; off < 64; off <<= 1) q += __shfl_xor(q, off);
      const float var = q * 0.015625f;
      const float y = dv * rsqrtf(var + EPS) * gv + bb;
      Xs[r][lane] = fmaxf(y, 0.0f);
    }
  }
  __syncthreads();

  // ---- layer 3 + max-pool: o = max_r (Xs @ Wout^T + bout) ----
  {
    const int c    = t & 127;
    const int half = t >> 7;          // rows half*16 .. half*16+15
    float acc[16];
#pragma unroll
    for (int i = 0; i < 16; ++i) acc[i] = bout[c];
    const float* w = Wout + c * 64;
    for (int kc = 0; kc < 16; ++kc) {
      const float w0 = w[4 * kc + 0], w1v = w[4 * kc + 1];
      const float w2v = w[4 * kc + 2], w3v = w[4 * kc + 3];
#pragma unroll
      for (int i = 0; i < 16; ++i) {
        const float4 xv = *reinterpret_cast<const float4*>(&Xs[half * 16 + i][4 * kc]);
        acc[i] = fmaf(xv.x, w0,  acc[i]);
        acc[i] = fmaf(xv.y, w1v, acc[i]);
        acc[i] = fmaf(xv.z, w2v, acc[i]);
        acc[i] = fmaf(xv.w, w3v, acc[i]);
      }
    }
    float mx = acc[0];
#pragma unroll
    for (int i = 1; i < 16; ++i) mx = fmaxf(mx, acc[i]);
    omax[half][c] = mx;
  }
  __syncthreads();

  if (t < 128) {
    out[(size_t)bm * OUTn + t] = fmaxf(omax[0][t], omax[1][t]);
  }
}

// ---------------------------------------------------------------------------
extern "C" void kernel_launch(void* const* d_in, const int* in_sizes, int n_in,
                              void* d_out, int out_size, void* d_ws, size_t ws_size,
                              hipStream_t stream)
{
  const float* xyz  = (const float*)d_in[0];
  const float* feat = (const float*)d_in[1];
  const float* W1   = (const float*)d_in[2];
  const float* b1   = (const float*)d_in[3];
  const float* g1   = (const float*)d_in[4];
  const float* be1  = (const float*)d_in[5];
  const float* W2   = (const float*)d_in[6];
  const float* b2   = (const float*)d_in[7];
  const float* g2   = (const float*)d_in[8];
  const float* be2  = (const float*)d_in[9];
  const float* Wout = (const float*)d_in[10];
  const float* bout = (const float*)d_in[11];

  float* outp = (float*)d_out;
  float* cent = outp;                             // (B, M, 3)
  float* o    = outp + (size_t)Bn * Mn * 3;       // (B, M, 128)

  fps_kernel<<<Bn, 1024, 0, stream>>>(xyz, cent);
  sa_kernel<<<Bn * Mn, 256, 0, stream>>>(xyz, feat,
                                         W1, b1, g1, be1,
                                         W2, b2, g2, be2,
                                         Wout, bout, cent, o);
}

// Round 4
// 2329.808 us; speedup vs baseline: 1.4229x; 1.4229x over previous
//
#include <hip/hip_runtime.h>
#include <math.h>

#define Bn   16
#define Nn   4096
#define Cn   64
#define Dn   67      // 3 + 64
#define Mn   1024
#define Kn   32
#define OUTn 128
#define EPS  1e-5f

// ---------------------------------------------------------------------------
// FPS: one block per batch, 256 threads (4 waves = 1/SIMD), 16 pts/thread in
// registers. Per step: local rescan (VALU, parallel across SIMDs), in-wave
// butterfly argmax, 4-partial LDS combine, ONE __syncthreads (parity buffers).
// Matches reference: d0 = ||p - p0||^2; step: nxt = argmax(d) (first-max
// tie-break), d = min(d, ||p - p[nxt]||^2). Writes centroid coords directly.
// ---------------------------------------------------------------------------
__global__ __launch_bounds__(256) void fps_kernel(
    const float* __restrict__ xyz, float* __restrict__ cent)
{
  __shared__ float pts[Nn * 3];     // 48 KB point cache
  __shared__ float pv[2][4];
  __shared__ int   pi[2][4];

  const int b = blockIdx.x;
  const int t = threadIdx.x;
  const float* src = xyz + (size_t)b * Nn * 3;

  // vectorized LDS fill (12288 floats = 3072 float4, 16B-aligned)
  {
    const float4* s4 = reinterpret_cast<const float4*>(src);
    float4* p4 = reinterpret_cast<float4*>(pts);
    for (int i = t; i < Nn * 3 / 4; i += 256) p4[i] = s4[i];
  }
  __syncthreads();

  const float c0x = pts[0], c0y = pts[1], c0z = pts[2];

  float px[16], py[16], pz[16], d[16];
  float bv = -1.0f; int bi = 0;
#pragma unroll
  for (int j = 0; j < 16; ++j) {
    const int n = j * 256 + t;
    px[j] = pts[n * 3 + 0];
    py[j] = pts[n * 3 + 1];
    pz[j] = pts[n * 3 + 2];
    const float dx = px[j] - c0x, dy = py[j] - c0y, dz = pz[j] - c0z;
    d[j] = (dx * dx + dy * dy) + dz * dz;
    if (d[j] > bv) { bv = d[j]; bi = n; }   // ascending n => first-max kept
  }

  if (t == 0) {
    float* o = cent + (size_t)b * Mn * 3;
    o[0] = c0x; o[1] = c0y; o[2] = c0z;
  }

  for (int m = 1; m < Mn; ++m) {
    // wave-level argmax butterfly (max value, tie -> lower index)
    float v = bv; int i0 = bi;
#pragma unroll
    for (int off = 1; off < 64; off <<= 1) {
      const float ov = __shfl_xor(v, off);
      const int   oi = __shfl_xor(i0, off);
      if (ov > v || (ov == v && oi < i0)) { v = ov; i0 = oi; }
    }
    const int par = m & 1;
    if ((t & 63) == 0) { pv[par][t >> 6] = v; pi[par][t >> 6] = i0; }
    __syncthreads();

    // every thread combines the 4 wave partials (broadcast LDS reads)
    float fv = pv[par][0]; int fi = pi[par][0];
#pragma unroll
    for (int q = 1; q < 4; ++q) {
      const float qv = pv[par][q]; const int qi = pi[par][q];
      if (qv > fv || (qv == fv && qi < fi)) { fv = qv; fi = qi; }
    }

    const float cx = pts[fi * 3 + 0];
    const float cy = pts[fi * 3 + 1];
    const float cz = pts[fi * 3 + 2];
    if (t == 0) {
      float* o = cent + ((size_t)b * Mn + m) * 3;
      o[0] = cx; o[1] = cy; o[2] = cz;
    }

    // fused distance update + local argmax rescan
    bv = -1.0f; bi = 0;
#pragma unroll
    for (int j = 0; j < 16; ++j) {
      const float dx = px[j] - cx, dy = py[j] - cy, dz = pz[j] - cz;
      const float nd = (dx * dx + dy * dy) + dz * dz;
      d[j] = fminf(d[j], nd);
      if (d[j] > bv) { bv = d[j]; bi = j * 256 + t; }
    }
  }
}

// ---------------------------------------------------------------------------
// Fused KNN + gather + MLP(3 layers, 2 LayerNorm+ReLU) + max-pool.
// One block (256 threads) per centroid (b, m); 16 points per thread.
// KNN: 32 iterative argmin extractions, (value, lower-index) tie-break ->
// identical selected SET to stable top_k(-d2, 32). d2 uses the reference
// formula (cc + pp) - 2*dot in f32.
// ---------------------------------------------------------------------------
__global__ __launch_bounds__(256) void sa_kernel(
    const float* __restrict__ xyz, const float* __restrict__ feat,
    const float* __restrict__ W1, const float* __restrict__ b1,
    const float* __restrict__ g1, const float* __restrict__ be1,
    const float* __restrict__ W2, const float* __restrict__ b2,
    const float* __restrict__ g2, const float* __restrict__ be2,
    const float* __restrict__ Wout, const float* __restrict__ bout,
    const float* __restrict__ cent, float* __restrict__ out)
{
  __shared__ float Xs[Kn][68];      // 32 x 67 (+pad), rows 272B (16B aligned)
  __shared__ float Hs[Kn][64];      // hidden activations
  __shared__ int   sel[Kn];
  __shared__ float pvv[2][4];
  __shared__ int   pii[2][4];
  __shared__ float omax[2][OUTn];

  const int bm = blockIdx.x;
  const int b  = bm >> 10;
  const int m  = bm & 1023;
  const int t  = threadIdx.x;

  const float* P = xyz  + (size_t)b * Nn * 3;
  const float* F = feat + (size_t)b * Nn * Cn;

  const float cx = cent[((size_t)b * Mn + m) * 3 + 0];
  const float cy = cent[((size_t)b * Mn + m) * 3 + 1];
  const float cz = cent[((size_t)b * Mn + m) * 3 + 2];
  const float cc = (cx * cx + cy * cy) + cz * cz;

  // ---- distances (reference formula) ----
  float d2[16];
#pragma unroll
  for (int j = 0; j < 16; ++j) {
    const int n = j * 256 + t;
    const float x = P[n * 3 + 0], y = P[n * 3 + 1], z = P[n * 3 + 2];
    const float pp = (x * x + y * y) + z * z;
    const float dt = (cx * x + cy * y) + cz * z;
    d2[j] = (cc + pp) - 2.0f * dt;
  }

  // cached per-thread min candidate
  float bv = d2[0]; int bslot = 0;
#pragma unroll
  for (int j = 1; j < 16; ++j)
    if (d2[j] < bv) { bv = d2[j]; bslot = j; }
  int bidx = bslot * 256 + t;

  // ---- 32 argmin extractions ----
  for (int s = 0; s < Kn; ++s) {
    float v = bv; int i0 = bidx;
#pragma unroll
    for (int off = 1; off < 64; off <<= 1) {
      const float ov = __shfl_xor(v, off);
      const int   oi = __shfl_xor(i0, off);
      if (ov < v || (ov == v && oi < i0)) { v = ov; i0 = oi; }
    }
    const int par = s & 1;
    if ((t & 63) == 0) { pvv[par][t >> 6] = v; pii[par][t >> 6] = i0; }
    __syncthreads();

    float fv = pvv[par][0]; int fi = pii[par][0];
#pragma unroll
    for (int q = 1; q < 4; ++q) {
      const float qv = pvv[par][q]; const int qi = pii[par][q];
      if (qv < fv || (qv == fv && qi < fi)) { fv = qv; fi = qi; }
    }
    if (t == 0) sel[s] = fi;

    if ((fi & 255) == t) {          // owner masks + rescans its 16 (registers)
      const int slot = fi >> 8;
#pragma unroll
      for (int j = 0; j < 16; ++j)
        if (j == slot) d2[j] = INFINITY;
      bv = INFINITY; bslot = 0;
#pragma unroll
      for (int j = 0; j < 16; ++j)
        if (d2[j] < bv) { bv = d2[j]; bslot = j; }
      bidx = bslot * 256 + t;
    }
  }
  __syncthreads();

  // ---- gather X = [p - c | features] ----
  {
    const int r  = t >> 3;    // 0..31
    const int l8 = t & 7;     // 0..7
    const int n  = sel[r];
    if (l8 == 0) {
      Xs[r][0] = P[n * 3 + 0] - cx;
      Xs[r][1] = P[n * 3 + 1] - cy;
      Xs[r][2] = P[n * 3 + 2] - cz;
    }
#pragma unroll
    for (int q = 0; q < 8; ++q) {
      const int c = l8 * 8 + q;
      Xs[r][3 + c] = F[(size_t)n * Cn + c];
    }
  }
  __syncthreads();

  // ---- layer 1: Hs = Xs @ W1^T + b1  (K = 67) ----
  {
    const int c  = t & 63;
    const int rs = t >> 6;    // wave id -> rows rs*8 .. rs*8+7
    float acc[8];
#pragma unroll
    for (int i = 0; i < 8; ++i) acc[i] = b1[c];
    const float* w = W1 + c * Dn;
    for (int kc = 0; kc < 16; ++kc) {
      const float w0 = w[4 * kc + 0], w1v = w[4 * kc + 1];
      const float w2v = w[4 * kc + 2], w3v = w[4 * kc + 3];
#pragma unroll
      for (int i = 0; i < 8; ++i) {
        const float4 xv = *reinterpret_cast<const float4*>(&Xs[rs * 8 + i][4 * kc]);
        acc[i] = fmaf(xv.x, w0,  acc[i]);
        acc[i] = fmaf(xv.y, w1v, acc[i]);
        acc[i] = fmaf(xv.z, w2v, acc[i]);
        acc[i] = fmaf(xv.w, w3v, acc[i]);
      }
    }
    {
      const float wt0 = w[64], wt1 = w[65], wt2 = w[66];
#pragma unroll
      for (int i = 0; i < 8; ++i) {
        const int r = rs * 8 + i;
        acc[i] = fmaf(Xs[r][64], wt0, acc[i]);
        acc[i] = fmaf(Xs[r][65], wt1, acc[i]);
        acc[i] = fmaf(Xs[r][66], wt2, acc[i]);
      }
    }
#pragma unroll
    for (int i = 0; i < 8; ++i) Hs[rs * 8 + i][c] = acc[i];
  }
  __syncthreads();

  // ---- LN1 + ReLU (rows of 64; one wave per 8 rows, lane = column) ----
  {
    const int lane = t & 63;
    const int wv   = t >> 6;
    const float gv = g1[lane], bb = be1[lane];
#pragma unroll
    for (int rr = 0; rr < 8; ++rr) {
      const int r = wv * 8 + rr;
      const float x = Hs[r][lane];
      float s = x;
#pragma unroll
      for (int off = 1; off < 64; off <<= 1) s += __shfl_xor(s, off);
      const float mu = s * 0.015625f;
      const float dv = x - mu;
      float q = dv * dv;
#pragma unroll
      for (int off = 1; off < 64; off <<= 1) q += __shfl_xor(q, off);
      const float var = q * 0.015625f;
      const float y = dv * rsqrtf(var + EPS) * gv + bb;
      Hs[r][lane] = fmaxf(y, 0.0f);
    }
  }
  __syncthreads();

  // ---- layer 2: Xs[.][0..63] = Hs @ W2^T + b2  (K = 64) ----
  {
    const int c  = t & 63;
    const int rs = t >> 6;
    float acc[8];
#pragma unroll
    for (int i = 0; i < 8; ++i) acc[i] = b2[c];
    const float* w = W2 + c * 64;
    for (int kc = 0; kc < 16; ++kc) {
      const float w0 = w[4 * kc + 0], w1v = w[4 * kc + 1];
      const float w2v = w[4 * kc + 2], w3v = w[4 * kc + 3];
#pragma unroll
      for (int i = 0; i < 8; ++i) {
        const float4 xv = *reinterpret_cast<const float4*>(&Hs[rs * 8 + i][4 * kc]);
        acc[i] = fmaf(xv.x, w0,  acc[i]);
        acc[i] = fmaf(xv.y, w1v, acc[i]);
        acc[i] = fmaf(xv.z, w2v, acc[i]);
        acc[i] = fmaf(xv.w, w3v, acc[i]);
      }
    }
#pragma unroll
    for (int i = 0; i < 8; ++i) Xs[rs * 8 + i][c] = acc[i];
  }
  __syncthreads();

  // ---- LN2 + ReLU (on Xs, stride 68) ----
  {
    const int lane = t & 63;
    const int wv   = t >> 6;
    const float gv = g2[lane], bb = be2[lane];
#pragma unroll
    for (int rr = 0; rr < 8; ++rr) {
      const int r = wv * 8 + rr;
      const float x = Xs[r][lane];
      float s = x;
#pragma unroll
      for (int off = 1; off < 64; off <<= 1) s += __shfl_xor(s, off);
      const float mu = s * 0.015625f;
      const float dv = x - mu;
      float q = dv * dv;
#pragma unroll
      for (int off = 1; off < 64; off <<= 1) q += __shfl_xor(q, off);
      const float var = q * 0.015625f;
      const float y = dv * rsqrtf(var + EPS) * gv + bb;
      Xs[r][lane] = fmaxf(y, 0.0f);
    }
  }
  __syncthreads();

  // ---- layer 3 + max-pool: o = max_r (Xs @ Wout^T + bout) ----
  {
    const int c    = t & 127;
    const int half = t >> 7;          // rows half*16 .. half*16+15
    float acc[16];
#pragma unroll
    for (int i = 0; i < 16; ++i) acc[i] = bout[c];
    const float* w = Wout + c * 64;
    for (int kc = 0; kc < 16; ++kc) {
      const float w0 = w[4 * kc + 0], w1v = w[4 * kc + 1];
      const float w2v = w[4 * kc + 2], w3v = w[4 * kc + 3];
#pragma unroll
      for (int i = 0; i < 16; ++i) {
        const float4 xv = *reinterpret_cast<const float4*>(&Xs[half * 16 + i][4 * kc]);
        acc[i] = fmaf(xv.x, w0,  acc[i]);
        acc[i] = fmaf(xv.y, w1v, acc[i]);
        acc[i] = fmaf(xv.z, w2v, acc[i]);
        acc[i] = fmaf(xv.w, w3v, acc[i]);
      }
    }
    float mx = acc[0];
#pragma unroll
    for (int i = 1; i < 16; ++i) mx = fmaxf(mx, acc[i]);
    omax[half][c] = mx;
  }
  __syncthreads();

  if (t < 128) {
    out[(size_t)bm * OUTn + t] = fmaxf(omax[0][t], omax[1][t]);
  }
}

// ---------------------------------------------------------------------------
extern "C" void kernel_launch(void* const* d_in, const int* in_sizes, int n_in,
                              void* d_out, int out_size, void* d_ws, size_t ws_size,
                              hipStream_t stream)
{
  const float* xyz  = (const float*)d_in[0];
  const float* feat = (const float*)d_in[1];
  const float* W1   = (const float*)d_in[2];
  const float* b1   = (const float*)d_in[3];
  const float* g1   = (const float*)d_in[4];
  const float* be1  = (const float*)d_in[5];
  const float* W2   = (const float*)d_in[6];
  const float* b2   = (const float*)d_in[7];
  const float* g2   = (const float*)d_in[8];
  const float* be2  = (const float*)d_in[9];
  const float* Wout = (const float*)d_in[10];
  const float* bout = (const float*)d_in[11];

  float* outp = (float*)d_out;
  float* cent = outp;                             // (B, M, 3)
  float* o    = outp + (size_t)Bn * Mn * 3;       // (B, M, 128)

  fps_kernel<<<Bn, 256, 0, stream>>>(xyz, cent);
  sa_kernel<<<Bn * Mn, 256, 0, stream>>>(xyz, feat,
                                         W1, b1, g1, be1,
                                         W2, b2, g2, be2,
                                         Wout, bout, cent, o);
}

// Round 5
// 1660.743 us; speedup vs baseline: 1.9962x; 1.4029x over previous
//
#include <hip/hip_runtime.h>
#include <math.h>

#define Bn   16
#define Nn   4096
#define Cn   64
#define Mn   1024
#define Kn   32
#define OUTn 128
#define EPS  1e-5f

typedef unsigned long long u64;
typedef unsigned int u32;

__device__ __forceinline__ u64 u64min(u64 a, u64 b) { return a < b ? a : b; }
__device__ __forceinline__ u64 u64max(u64 a, u64 b) { return a > b ? a : b; }

// ---------------------------------------------------------------------------
// FPS: one block/batch, 256 threads, 16 pts/thread in regs.
// Packed keys: (bits(d)<<32)|~n  (d>=0 so float bits are monotonic); u64 MAX
// == (max d, tie -> lowest n) == jnp.argmax first-max semantics.
// Per step: 16 indep dist-updates -> depth-4 tree max -> 6-stage u64 butterfly
// -> 4-partial LDS combine (parity buffers, ONE barrier) -> b128 centroid read.
// ---------------------------------------------------------------------------
__global__ __launch_bounds__(256) void fps_kernel(
    const float* __restrict__ xyz, float* __restrict__ cent)
{
  __shared__ float4 pts4[Nn];          // 64 KB
  __shared__ u64 pvq[2][4];

  const int b = blockIdx.x;
  const int t = threadIdx.x;
  const float* src = xyz + (size_t)b * Nn * 3;

  for (int i = t; i < Nn; i += 256) {
    pts4[i] = make_float4(src[3*i+0], src[3*i+1], src[3*i+2], 0.0f);
  }
  __syncthreads();

  const float4 c0 = pts4[0];

  float px[16], py[16], pz[16], d[16];
#pragma unroll
  for (int j = 0; j < 16; ++j) {
    const int n = j * 256 + t;
    const float4 p = pts4[n];
    px[j] = p.x; py[j] = p.y; pz[j] = p.z;
    const float dx = px[j] - c0.x, dy = py[j] - c0.y, dz = pz[j] - c0.z;
    d[j] = (dx * dx + dy * dy) + dz * dz;
  }

  if (t == 0) {
    float* o = cent + (size_t)b * Mn * 3;
    o[0] = c0.x; o[1] = c0.y; o[2] = c0.z;
  }

  for (int m = 1; m < Mn; ++m) {
    // build packed keys + depth-4 tree max
    u64 k[16];
#pragma unroll
    for (int j = 0; j < 16; ++j)
      k[j] = ((u64)__float_as_uint(d[j]) << 32) | (u32)(~(j * 256 + t));
#pragma unroll
    for (int st = 1; st < 16; st <<= 1)
#pragma unroll
      for (int j = 0; j < 16; j += (st << 1))
        k[j] = u64max(k[j], k[j + st]);
    u64 bk = k[0];

    // 6-stage wave butterfly (all lanes get wave max)
#pragma unroll
    for (int off = 1; off < 64; off <<= 1) {
      const u64 o = __shfl_xor(bk, off);
      bk = u64max(bk, o);
    }
    const int par = m & 1;
    if ((t & 63) == 0) pvq[par][t >> 6] = bk;
    __syncthreads();

    u64 f = u64max(u64max(pvq[par][0], pvq[par][1]),
                   u64max(pvq[par][2], pvq[par][3]));
    const int fi = (int)(~(u32)f);      // low word was ~n

    const float4 cp = pts4[fi];
    if (t == 0) {
      float* o = cent + ((size_t)b * Mn + m) * 3;
      o[0] = cp.x; o[1] = cp.y; o[2] = cp.z;
    }

#pragma unroll
    for (int j = 0; j < 16; ++j) {
      const float dx = px[j] - cp.x, dy = py[j] - cp.y, dz = pz[j] - cp.z;
      const float nd = (dx * dx + dy * dy) + dz * dz;
      d[j] = fminf(d[j], nd);
    }
  }
}

// ---------------------------------------------------------------------------
// KNN: one block (256 thr) per centroid. Packed keys (mono(bits(d2))<<32)|n;
// u64 MIN == (min d2, tie -> lowest idx) == stable top_k set. 32 extractions,
// one barrier each (parity buffers). Writes 32 indices into the o-region of
// d_out (punned as int) -- mlp_kernel reads them before overwriting.
// d2 uses the exact reference formula (cc+pp)-2*dot in f32 (same as the
// passing round-1 kernel).
// ---------------------------------------------------------------------------
__global__ __launch_bounds__(256) void knn_kernel(
    const float* __restrict__ xyz, const float* __restrict__ cent,
    int* __restrict__ osel)
{
  __shared__ u64 pvq[2][4];

  const int bm = blockIdx.x;
  const int b  = bm >> 10;
  const int t  = threadIdx.x;
  const float* P = xyz + (size_t)b * Nn * 3;

  const float cx = cent[(size_t)bm * 3 + 0];
  const float cy = cent[(size_t)bm * 3 + 1];
  const float cz = cent[(size_t)bm * 3 + 2];
  const float cc2 = (cx * cx + cy * cy) + cz * cz;

  u64 key[16];
#pragma unroll
  for (int j = 0; j < 16; ++j) {
    const int n = j * 256 + t;
    const float x = P[n*3+0], y = P[n*3+1], z = P[n*3+2];
    const float pp = (x * x + y * y) + z * z;
    const float dt = (cx * x + cy * y) + cz * z;
    const float d2 = (cc2 + pp) - 2.0f * dt;
    const u32 bu = __float_as_uint(d2);
    const u32 mo = bu ^ (0x80000000u | (u32)((int)bu >> 31)); // order-preserving
    key[j] = ((u64)mo << 32) | (u32)n;
  }

  // local min (tree, keys preserved)
  u64 bk;
  {
    u64 tmp[16];
#pragma unroll
    for (int j = 0; j < 16; ++j) tmp[j] = key[j];
#pragma unroll
    for (int st = 1; st < 16; st <<= 1)
#pragma unroll
      for (int j = 0; j < 16; j += (st << 1))
        tmp[j] = u64min(tmp[j], tmp[j + st]);
    bk = tmp[0];
  }

  int myfi = 0;
  for (int s = 0; s < Kn; ++s) {
    u64 v = bk;
#pragma unroll
    for (int off = 1; off < 64; off <<= 1) {
      const u64 o = __shfl_xor(v, off);
      v = u64min(v, o);
    }
    const int par = s & 1;
    if ((t & 63) == 0) pvq[par][t >> 6] = v;
    __syncthreads();

    const u64 f = u64min(u64min(pvq[par][0], pvq[par][1]),
                         u64min(pvq[par][2], pvq[par][3]));
    const int fi = (int)(u32)f;
    if (t == s) myfi = fi;

    if ((fi & 255) == t) {            // owner invalidates + rescans (tree)
      const int slot = fi >> 8;
#pragma unroll
      for (int j = 0; j < 16; ++j)
        if (j == slot) key[j] = ~0ull;
      u64 tmp[16];
#pragma unroll
      for (int j = 0; j < 16; ++j) tmp[j] = key[j];
#pragma unroll
      for (int st = 1; st < 16; st <<= 1)
#pragma unroll
        for (int j = 0; j < 16; j += (st << 1))
          tmp[j] = u64min(tmp[j], tmp[j + st]);
      bk = tmp[0];
    }
  }

  if (t < Kn) osel[(size_t)bm * 128 + t] = myfi;
}

// ---------------------------------------------------------------------------
// MLP: one block (256 thr) per 4 centroids = 128 rows.
// X layout in LDS A[128][68]: cols 0-63 = features, 64-66 = p-c, 67 = 0.
// lane=row scheme: wave w -> rows 64*(w&1)+lane, col-block 32*(w>>1) (64 for
// layer3). Weights via wave-uniform scalar loads (readfirstlane'd col base ->
// s_load broadcast, v_fma with SGPR operand). LN: per-thread partial over its
// 32 cols + one cross-wave LDS exchange; var = E[x^2]-mu^2. A reused for H1,H2.
// Maxpool: 5-stage shfl_xor within 32-lane halves + predicated stores.
// ---------------------------------------------------------------------------
__global__ __launch_bounds__(256) void mlp_kernel(
    const float* __restrict__ xyz, const float* __restrict__ feat,
    const float* __restrict__ W1, const float* __restrict__ b1,
    const float* __restrict__ g1, const float* __restrict__ be1,
    const float* __restrict__ W2, const float* __restrict__ b2,
    const float* __restrict__ g2, const float* __restrict__ be2,
    const float* __restrict__ Wout, const float* __restrict__ bout,
    const float* __restrict__ cent, float* __restrict__ out)
{
  __shared__ float A[128][68];
  __shared__ float lnS[2][128];
  __shared__ float lnQ[2][128];

  const int bm0 = blockIdx.x << 2;          // 4 centroids, same batch (1024%4==0)
  const int b   = bm0 >> 10;
  const int t   = threadIdx.x;
  const int wid = __builtin_amdgcn_readfirstlane(t >> 6);
  const int lane = t & 63;

  const float* F = feat + (size_t)b * Nn * Cn;
  const float* P = xyz  + (size_t)b * Nn * 3;
  const int* osel = (const int*)out;

  // ---- gather: 2 threads per row ----
  {
    const int row = t >> 1, half = t & 1;
    const int g = bm0 + (row >> 5);
    const int n = osel[(size_t)g * 128 + (row & 31)];
    const float4* f4 = (const float4*)(F + (size_t)n * Cn + half * 32);
#pragma unroll
    for (int q = 0; q < 8; ++q)
      *(float4*)&A[row][half * 32 + q * 4] = f4[q];
    if (half) {
      A[row][64] = P[n*3+0] - cent[(size_t)g*3+0];
      A[row][65] = P[n*3+1] - cent[(size_t)g*3+1];
      A[row][66] = P[n*3+2] - cent[(size_t)g*3+2];
      A[row][67] = 0.0f;
    }
  }
  __syncthreads();

  const int row = ((wid & 1) << 6) + lane;
  const int c0  = (wid >> 1) << 5;
  const int slot = wid >> 1;

  float acc[32];

  // ---- layer 1 (K=67): X cols 0..63 -> W1 cols 3..66; X 64..66 -> W1 0..2 ----
  {
    const float* w1b = W1 + (size_t)c0 * 67;
#pragma unroll
    for (int cc = 0; cc < 32; ++cc) acc[cc] = b1[c0 + cc];
    for (int k4 = 0; k4 < 16; ++k4) {
      const float4 xv = *(const float4*)&A[row][k4 * 4];
#pragma unroll
      for (int cc = 0; cc < 32; ++cc) {
        const float* w = w1b + cc * 67 + k4 * 4 + 3;
        acc[cc] = fmaf(xv.x, w[0], acc[cc]);
        acc[cc] = fmaf(xv.y, w[1], acc[cc]);
        acc[cc] = fmaf(xv.z, w[2], acc[cc]);
        acc[cc] = fmaf(xv.w, w[3], acc[cc]);
      }
    }
    const float x0 = A[row][64], x1 = A[row][65], x2 = A[row][66];
#pragma unroll
    for (int cc = 0; cc < 32; ++cc) {
      const float* w = w1b + cc * 67;
      acc[cc] = fmaf(x0, w[0], acc[cc]);
      acc[cc] = fmaf(x1, w[1], acc[cc]);
      acc[cc] = fmaf(x2, w[2], acc[cc]);
    }
  }

  // ---- LN1 + ReLU -> A ----
  {
    float s = 0.0f, q = 0.0f;
#pragma unroll
    for (int cc = 0; cc < 32; ++cc) { s += acc[cc]; q = fmaf(acc[cc], acc[cc], q); }
    lnS[slot][row] = s; lnQ[slot][row] = q;
    __syncthreads();                       // lnbuf ready AND all layer-1 A-reads done
    const float st = s + lnS[slot ^ 1][row];
    const float qt = q + lnQ[slot ^ 1][row];
    const float mu = st * 0.015625f;
    const float var = qt * 0.015625f - mu * mu;
    const float rs = rsqrtf(var + EPS);
#pragma unroll
    for (int cc = 0; cc < 32; ++cc) {
      const float y = (acc[cc] - mu) * rs * g1[c0 + cc] + be1[c0 + cc];
      acc[cc] = fmaxf(y, 0.0f);
    }
#pragma unroll
    for (int c4 = 0; c4 < 8; ++c4)
      *(float4*)&A[row][c0 + c4 * 4] =
          make_float4(acc[c4*4], acc[c4*4+1], acc[c4*4+2], acc[c4*4+3]);
  }
  __syncthreads();

  // ---- layer 2 (K=64) ----
  {
    const float* w2b = W2 + (size_t)c0 * 64;
    float a2[32];
#pragma unroll
    for (int cc = 0; cc < 32; ++cc) a2[cc] = b2[c0 + cc];
    for (int k4 = 0; k4 < 16; ++k4) {
      const float4 xv = *(const float4*)&A[row][k4 * 4];
#pragma unroll
      for (int cc = 0; cc < 32; ++cc) {
        const float* w = w2b + cc * 64 + k4 * 4;
        a2[cc] = fmaf(xv.x, w[0], a2[cc]);
        a2[cc] = fmaf(xv.y, w[1], a2[cc]);
        a2[cc] = fmaf(xv.z, w[2], a2[cc]);
        a2[cc] = fmaf(xv.w, w[3], a2[cc]);
      }
    }
#pragma unroll
    for (int cc = 0; cc < 32; ++cc) acc[cc] = a2[cc];
  }

  // ---- LN2 + ReLU -> A ----
  {
    float s = 0.0f, q = 0.0f;
#pragma unroll
    for (int cc = 0; cc < 32; ++cc) { s += acc[cc]; q = fmaf(acc[cc], acc[cc], q); }
    lnS[slot][row] = s; lnQ[slot][row] = q;
    __syncthreads();
    const float st = s + lnS[slot ^ 1][row];
    const float qt = q + lnQ[slot ^ 1][row];
    const float mu = st * 0.015625f;
    const float var = qt * 0.015625f - mu * mu;
    const float rs = rsqrtf(var + EPS);
#pragma unroll
    for (int cc = 0; cc < 32; ++cc) {
      const float y = (acc[cc] - mu) * rs * g2[c0 + cc] + be2[c0 + cc];
      acc[cc] = fmaxf(y, 0.0f);
    }
#pragma unroll
    for (int c4 = 0; c4 < 8; ++c4)
      *(float4*)&A[row][c0 + c4 * 4] =
          make_float4(acc[c4*4], acc[c4*4+1], acc[c4*4+2], acc[c4*4+3]);
  }
  __syncthreads();

  // ---- layer 3 (K=64, 64 cols/wave) + maxpool + store ----
  {
    const int c03 = (wid >> 1) << 6;
    const float* w3b = Wout + (size_t)c03 * 64;
    float a3[64];
#pragma unroll
    for (int cc = 0; cc < 64; ++cc) a3[cc] = bout[c03 + cc];
    for (int k4 = 0; k4 < 16; ++k4) {
      const float4 xv = *(const float4*)&A[row][k4 * 4];
#pragma unroll
      for (int cc = 0; cc < 64; ++cc) {
        const float* w = w3b + cc * 64 + k4 * 4;
        a3[cc] = fmaf(xv.x, w[0], a3[cc]);
        a3[cc] = fmaf(xv.y, w[1], a3[cc]);
        a3[cc] = fmaf(xv.z, w[2], a3[cc]);
        a3[cc] = fmaf(xv.w, w[3], a3[cc]);
      }
    }
    // pool over 32 rows (lanes within 32-lane half)
#pragma unroll
    for (int cc = 0; cc < 64; ++cc) {
      float v = a3[cc];
      v = fmaxf(v, __shfl_xor(v, 1));
      v = fmaxf(v, __shfl_xor(v, 2));
      v = fmaxf(v, __shfl_xor(v, 4));
      v = fmaxf(v, __shfl_xor(v, 8));
      v = fmaxf(v, __shfl_xor(v, 16));
      a3[cc] = v;
    }
    const int g = bm0 + ((wid & 1) << 1) + (lane >> 5);
    float* og = out + (size_t)g * OUTn + c03;
#pragma unroll
    for (int cc = 0; cc < 64; ++cc)
      if ((lane & 31) == (cc & 31)) og[cc] = a3[cc];
  }
}

// ---------------------------------------------------------------------------
extern "C" void kernel_launch(void* const* d_in, const int* in_sizes, int n_in,
                              void* d_out, int out_size, void* d_ws, size_t ws_size,
                              hipStream_t stream)
{
  const float* xyz  = (const float*)d_in[0];
  const float* feat = (const float*)d_in[1];
  const float* W1   = (const float*)d_in[2];
  const float* b1   = (const float*)d_in[3];
  const float* g1   = (const float*)d_in[4];
  const float* be1  = (const float*)d_in[5];
  const float* W2   = (const float*)d_in[6];
  const float* b2   = (const float*)d_in[7];
  const float* g2   = (const float*)d_in[8];
  const float* be2  = (const float*)d_in[9];
  const float* Wout = (const float*)d_in[10];
  const float* bout = (const float*)d_in[11];

  float* outp = (float*)d_out;
  float* cent = outp;                             // (B, M, 3)
  float* o    = outp + (size_t)Bn * Mn * 3;       // (B, M, 128)

  fps_kernel<<<Bn, 256, 0, stream>>>(xyz, cent);
  knn_kernel<<<Bn * Mn, 256, 0, stream>>>(xyz, cent, (int*)o);
  mlp_kernel<<<Bn * Mn / 4, 256, 0, stream>>>(xyz, feat,
                                              W1, b1, g1, be1,
                                              W2, b2, g2, be2,
                                              Wout, bout, cent, o);
}

// Round 6
// 1480.233 us; speedup vs baseline: 2.2396x; 1.1219x over previous
//
#include <hip/hip_runtime.h>
#include <math.h>

#define Bn   16
#define Nn   4096
#define Cn   64
#define Mn   1024
#define Kn   32
#define OUTn 128
#define EPS  1e-5f

typedef unsigned long long u64;
typedef unsigned int u32;

__device__ __forceinline__ u64 u64min(u64 a, u64 b) { return a < b ? a : b; }
__device__ __forceinline__ u64 u64max(u64 a, u64 b) { return a > b ? a : b; }

// DPP move of a u64 (2x i32 update_dpp). old = x -> invalid/masked lanes keep x,
// which is the identity for both max and min combines.
template<int CTRL>
__device__ __forceinline__ u64 dpp_u64(u64 x) {
  union { u64 q; u32 w[2]; } in, out;
  in.q = x;
  out.w[0] = (u32)__builtin_amdgcn_update_dpp((int)in.w[0], (int)in.w[0], CTRL, 0xf, 0xf, false);
  out.w[1] = (u32)__builtin_amdgcn_update_dpp((int)in.w[1], (int)in.w[1], CTRL, 0xf, 0xf, false);
  return out.q;
}

// Canonical GCN wave64 reduce: row_shr 1,2,4,8 -> bcast15 -> bcast31.
// Result valid in lane 63 only. Pure VALU (~10-15 cy/stage) vs ds_swizzle
// butterfly (~120 cy/stage LDS latency).
__device__ __forceinline__ u64 wave_max_dpp(u64 v) {
  v = u64max(v, dpp_u64<0x111>(v));
  v = u64max(v, dpp_u64<0x112>(v));
  v = u64max(v, dpp_u64<0x114>(v));
  v = u64max(v, dpp_u64<0x118>(v));
  v = u64max(v, dpp_u64<0x142>(v));
  v = u64max(v, dpp_u64<0x143>(v));
  return v;
}
__device__ __forceinline__ u64 wave_min_dpp(u64 v) {
  v = u64min(v, dpp_u64<0x111>(v));
  v = u64min(v, dpp_u64<0x112>(v));
  v = u64min(v, dpp_u64<0x114>(v));
  v = u64min(v, dpp_u64<0x118>(v));
  v = u64min(v, dpp_u64<0x142>(v));
  v = u64min(v, dpp_u64<0x143>(v));
  return v;
}

// ---------------------------------------------------------------------------
// FPS: one block/batch, 256 threads, 16 pts/thread in regs.
// Packed keys: (bits(d)<<32)|~n  (d>=0 -> monotonic bits); u64 MAX ==
// (max d, tie -> lowest n) == jnp.argmax first-max semantics.
// Per step: 16 indep dist-updates -> depth-4 tree max -> DPP wave reduce
// (lane63) -> 4-partial LDS combine (parity buffers, ONE barrier).
// ---------------------------------------------------------------------------
__global__ __launch_bounds__(256) void fps_kernel(
    const float* __restrict__ xyz, float* __restrict__ cent)
{
  __shared__ float4 pts4[Nn];          // 64 KB
  __shared__ __align__(16) u64 pvq[2][4];

  const int b = blockIdx.x;
  const int t = threadIdx.x;
  const float* src = xyz + (size_t)b * Nn * 3;

  for (int i = t; i < Nn; i += 256) {
    pts4[i] = make_float4(src[3*i+0], src[3*i+1], src[3*i+2], 0.0f);
  }
  __syncthreads();

  const float4 c0 = pts4[0];

  float px[16], py[16], pz[16], d[16];
  u32 ninv[16];
#pragma unroll
  for (int j = 0; j < 16; ++j) {
    const int n = j * 256 + t;
    ninv[j] = (u32)(~n);
    const float4 p = pts4[n];
    px[j] = p.x; py[j] = p.y; pz[j] = p.z;
    const float dx = px[j] - c0.x, dy = py[j] - c0.y, dz = pz[j] - c0.z;
    d[j] = (dx * dx + dy * dy) + dz * dz;
  }

  if (t == 0) {
    float* o = cent + (size_t)b * Mn * 3;
    o[0] = c0.x; o[1] = c0.y; o[2] = c0.z;
  }

  for (int m = 1; m < Mn; ++m) {
    // build packed keys + depth-4 tree max
    u64 k[16];
#pragma unroll
    for (int j = 0; j < 16; ++j)
      k[j] = ((u64)__float_as_uint(d[j]) << 32) | ninv[j];
#pragma unroll
    for (int st = 1; st < 16; st <<= 1)
#pragma unroll
      for (int j = 0; j < 16; j += (st << 1))
        k[j] = u64max(k[j], k[j + st]);

    const u64 bk = wave_max_dpp(k[0]);
    const int par = m & 1;
    if ((t & 63) == 63) pvq[par][t >> 6] = bk;
    __syncthreads();

    const u64 f = u64max(u64max(pvq[par][0], pvq[par][1]),
                         u64max(pvq[par][2], pvq[par][3]));
    const int fi = (int)(~(u32)f);      // low word was ~n

    const float4 cp = pts4[fi];
    if (t == 0) {
      float* o = cent + ((size_t)b * Mn + m) * 3;
      o[0] = cp.x; o[1] = cp.y; o[2] = cp.z;
    }

#pragma unroll
    for (int j = 0; j < 16; ++j) {
      const float dx = px[j] - cp.x, dy = py[j] - cp.y, dz = pz[j] - cp.z;
      const float nd = (dx * dx + dy * dy) + dz * dz;
      d[j] = fminf(d[j], nd);
    }
  }
}

// ---------------------------------------------------------------------------
// KNN: one block (256 thr) per centroid. Packed keys (mono(bits(d2))<<32)|n;
// u64 MIN == (min d2, tie -> lowest idx) == stable top_k set. 32 extractions,
// one barrier each (parity buffers), DPP wave reduce. Writes 32 indices into
// the o-region of d_out (punned as int) -- mlp_kernel reads them before
// overwriting. d2 uses the exact reference formula (cc+pp)-2*dot in f32.
// ---------------------------------------------------------------------------
__global__ __launch_bounds__(256) void knn_kernel(
    const float* __restrict__ xyz, const float* __restrict__ cent,
    int* __restrict__ osel)
{
  __shared__ __align__(16) u64 pvq[2][4];

  const int bm = blockIdx.x;
  const int b  = bm >> 10;
  const int t  = threadIdx.x;
  const float* P = xyz + (size_t)b * Nn * 3;

  const float cx = cent[(size_t)bm * 3 + 0];
  const float cy = cent[(size_t)bm * 3 + 1];
  const float cz = cent[(size_t)bm * 3 + 2];
  const float cc2 = (cx * cx + cy * cy) + cz * cz;

  u64 key[16];
#pragma unroll
  for (int j = 0; j < 16; ++j) {
    const int n = j * 256 + t;
    const float x = P[n*3+0], y = P[n*3+1], z = P[n*3+2];
    const float pp = (x * x + y * y) + z * z;
    const float dt = (cx * x + cy * y) + cz * z;
    const float d2 = (cc2 + pp) - 2.0f * dt;
    const u32 bu = __float_as_uint(d2);
    const u32 mo = bu ^ (0x80000000u | (u32)((int)bu >> 31)); // order-preserving
    key[j] = ((u64)mo << 32) | (u32)n;
  }

  // local min (tree, keys preserved)
  u64 bk;
  {
    u64 tmp[16];
#pragma unroll
    for (int j = 0; j < 16; ++j) tmp[j] = key[j];
#pragma unroll
    for (int st = 1; st < 16; st <<= 1)
#pragma unroll
      for (int j = 0; j < 16; j += (st << 1))
        tmp[j] = u64min(tmp[j], tmp[j + st]);
    bk = tmp[0];
  }

  int myfi = 0;
  for (int s = 0; s < Kn; ++s) {
    const u64 v = wave_min_dpp(bk);
    const int par = s & 1;
    if ((t & 63) == 63) pvq[par][t >> 6] = v;
    __syncthreads();

    const u64 f = u64min(u64min(pvq[par][0], pvq[par][1]),
                         u64min(pvq[par][2], pvq[par][3]));
    const int fi = (int)(u32)f;
    if (t == s) myfi = fi;

    if ((fi & 255) == t) {            // owner invalidates + rescans (tree)
      const int slot = fi >> 8;
#pragma unroll
      for (int j = 0; j < 16; ++j)
        if (j == slot) key[j] = ~0ull;
      u64 tmp[16];
#pragma unroll
      for (int j = 0; j < 16; ++j) tmp[j] = key[j];
#pragma unroll
      for (int st = 1; st < 16; st <<= 1)
#pragma unroll
        for (int j = 0; j < 16; j += (st << 1))
          tmp[j] = u64min(tmp[j], tmp[j + st]);
      bk = tmp[0];
    }
  }

  if (t < Kn) osel[(size_t)bm * 128 + t] = myfi;
}

// ---------------------------------------------------------------------------
// MLP: one block (256 thr) per 4 centroids = 128 rows.
// X layout in LDS A[128][68]: cols 0-63 = features, 64-66 = p-c, 67 = 0.
// lane=row scheme: wave w -> rows 64*(w&1)+lane, col-block 32*(w>>1) (64 for
// layer3). Weights via wave-uniform scalar loads. LN: per-thread partial over
// its 32 cols + one cross-wave LDS exchange; var = E[x^2]-mu^2. A reused.
// Maxpool: 5-stage shfl_xor within 32-lane halves + predicated stores.
// ---------------------------------------------------------------------------
__global__ __launch_bounds__(256) void mlp_kernel(
    const float* __restrict__ xyz, const float* __restrict__ feat,
    const float* __restrict__ W1, const float* __restrict__ b1,
    const float* __restrict__ g1, const float* __restrict__ be1,
    const float* __restrict__ W2, const float* __restrict__ b2,
    const float* __restrict__ g2, const float* __restrict__ be2,
    const float* __restrict__ Wout, const float* __restrict__ bout,
    const float* __restrict__ cent, float* __restrict__ out)
{
  __shared__ float A[128][68];
  __shared__ float lnS[2][128];
  __shared__ float lnQ[2][128];

  const int bm0 = blockIdx.x << 2;          // 4 centroids, same batch (1024%4==0)
  const int b   = bm0 >> 10;
  const int t   = threadIdx.x;
  const int wid = __builtin_amdgcn_readfirstlane(t >> 6);
  const int lane = t & 63;

  const float* F = feat + (size_t)b * Nn * Cn;
  const float* P = xyz  + (size_t)b * Nn * 3;
  const int* osel = (const int*)out;

  // ---- gather: 2 threads per row ----
  {
    const int row = t >> 1, half = t & 1;
    const int g = bm0 + (row >> 5);
    const int n = osel[(size_t)g * 128 + (row & 31)];
    const float4* f4 = (const float4*)(F + (size_t)n * Cn + half * 32);
#pragma unroll
    for (int q = 0; q < 8; ++q)
      *(float4*)&A[row][half * 32 + q * 4] = f4[q];
    if (half) {
      A[row][64] = P[n*3+0] - cent[(size_t)g*3+0];
      A[row][65] = P[n*3+1] - cent[(size_t)g*3+1];
      A[row][66] = P[n*3+2] - cent[(size_t)g*3+2];
      A[row][67] = 0.0f;
    }
  }
  __syncthreads();

  const int row = ((wid & 1) << 6) + lane;
  const int c0  = (wid >> 1) << 5;
  const int slot = wid >> 1;

  float acc[32];

  // ---- layer 1 (K=67): X cols 0..63 -> W1 cols 3..66; X 64..66 -> W1 0..2 ----
  {
    const float* w1b = W1 + (size_t)c0 * 67;
#pragma unroll
    for (int cc = 0; cc < 32; ++cc) acc[cc] = b1[c0 + cc];
    for (int k4 = 0; k4 < 16; ++k4) {
      const float4 xv = *(const float4*)&A[row][k4 * 4];
#pragma unroll
      for (int cc = 0; cc < 32; ++cc) {
        const float* w = w1b + cc * 67 + k4 * 4 + 3;
        acc[cc] = fmaf(xv.x, w[0], acc[cc]);
        acc[cc] = fmaf(xv.y, w[1], acc[cc]);
        acc[cc] = fmaf(xv.z, w[2], acc[cc]);
        acc[cc] = fmaf(xv.w, w[3], acc[cc]);
      }
    }
    const float x0 = A[row][64], x1 = A[row][65], x2 = A[row][66];
#pragma unroll
    for (int cc = 0; cc < 32; ++cc) {
      const float* w = w1b + cc * 67;
      acc[cc] = fmaf(x0, w[0], acc[cc]);
      acc[cc] = fmaf(x1, w[1], acc[cc]);
      acc[cc] = fmaf(x2, w[2], acc[cc]);
    }
  }

  // ---- LN1 + ReLU -> A ----
  {
    float s = 0.0f, q = 0.0f;
#pragma unroll
    for (int cc = 0; cc < 32; ++cc) { s += acc[cc]; q = fmaf(acc[cc], acc[cc], q); }
    lnS[slot][row] = s; lnQ[slot][row] = q;
    __syncthreads();                       // lnbuf ready AND all layer-1 A-reads done
    const float st = s + lnS[slot ^ 1][row];
    const float qt = q + lnQ[slot ^ 1][row];
    const float mu = st * 0.015625f;
    const float var = qt * 0.015625f - mu * mu;
    const float rs = rsqrtf(var + EPS);
#pragma unroll
    for (int cc = 0; cc < 32; ++cc) {
      const float y = (acc[cc] - mu) * rs * g1[c0 + cc] + be1[c0 + cc];
      acc[cc] = fmaxf(y, 0.0f);
    }
#pragma unroll
    for (int c4 = 0; c4 < 8; ++c4)
      *(float4*)&A[row][c0 + c4 * 4] =
          make_float4(acc[c4*4], acc[c4*4+1], acc[c4*4+2], acc[c4*4+3]);
  }
  __syncthreads();

  // ---- layer 2 (K=64) ----
  {
    const float* w2b = W2 + (size_t)c0 * 64;
    float a2[32];
#pragma unroll
    for (int cc = 0; cc < 32; ++cc) a2[cc] = b2[c0 + cc];
    for (int k4 = 0; k4 < 16; ++k4) {
      const float4 xv = *(const float4*)&A[row][k4 * 4];
#pragma unroll
      for (int cc = 0; cc < 32; ++cc) {
        const float* w = w2b + cc * 64 + k4 * 4;
        a2[cc] = fmaf(xv.x, w[0], a2[cc]);
        a2[cc] = fmaf(xv.y, w[1], a2[cc]);
        a2[cc] = fmaf(xv.z, w[2], a2[cc]);
        a2[cc] = fmaf(xv.w, w[3], a2[cc]);
      }
    }
#pragma unroll
    for (int cc = 0; cc < 32; ++cc) acc[cc] = a2[cc];
  }

  // ---- LN2 + ReLU -> A ----
  {
    float s = 0.0f, q = 0.0f;
#pragma unroll
    for (int cc = 0; cc < 32; ++cc) { s += acc[cc]; q = fmaf(acc[cc], acc[cc], q); }
    lnS[slot][row] = s; lnQ[slot][row] = q;
    __syncthreads();
    const float st = s + lnS[slot ^ 1][row];
    const float qt = q + lnQ[slot ^ 1][row];
    const float mu = st * 0.015625f;
    const float var = qt * 0.015625f - mu * mu;
    const float rs = rsqrtf(var + EPS);
#pragma unroll
    for (int cc = 0; cc < 32; ++cc) {
      const float y = (acc[cc] - mu) * rs * g2[c0 + cc] + be2[c0 + cc];
      acc[cc] = fmaxf(y, 0.0f);
    }
#pragma unroll
    for (int c4 = 0; c4 < 8; ++c4)
      *(float4*)&A[row][c0 + c4 * 4] =
          make_float4(acc[c4*4], acc[c4*4+1], acc[c4*4+2], acc[c4*4+3]);
  }
  __syncthreads();

  // ---- layer 3 (K=64, 64 cols/wave) + maxpool + store ----
  {
    const int c03 = (wid >> 1) << 6;
    const float* w3b = Wout + (size_t)c03 * 64;
    float a3[64];
#pragma unroll
    for (int cc = 0; cc < 64; ++cc) a3[cc] = bout[c03 + cc];
    for (int k4 = 0; k4 < 16; ++k4) {
      const float4 xv = *(const float4*)&A[row][k4 * 4];
#pragma unroll
      for (int cc = 0; cc < 64; ++cc) {
        const float* w = w3b + cc * 64 + k4 * 4;
        a3[cc] = fmaf(xv.x, w[0], a3[cc]);
        a3[cc] = fmaf(xv.y, w[1], a3[cc]);
        a3[cc] = fmaf(xv.z, w[2], a3[cc]);
        a3[cc] = fmaf(xv.w, w[3], a3[cc]);
      }
    }
    // pool over 32 rows (lanes within 32-lane half)
#pragma unroll
    for (int cc = 0; cc < 64; ++cc) {
      float v = a3[cc];
      v = fmaxf(v, __shfl_xor(v, 1));
      v = fmaxf(v, __shfl_xor(v, 2));
      v = fmaxf(v, __shfl_xor(v, 4));
      v = fmaxf(v, __shfl_xor(v, 8));
      v = fmaxf(v, __shfl_xor(v, 16));
      a3[cc] = v;
    }
    const int g = bm0 + ((wid & 1) << 1) + (lane >> 5);
    float* og = out + (size_t)g * OUTn + c03;
#pragma unroll
    for (int cc = 0; cc < 64; ++cc)
      if ((lane & 31) == (cc & 31)) og[cc] = a3[cc];
  }
}

// ---------------------------------------------------------------------------
extern "C" void kernel_launch(void* const* d_in, const int* in_sizes, int n_in,
                              void* d_out, int out_size, void* d_ws, size_t ws_size,
                              hipStream_t stream)
{
  const float* xyz  = (const float*)d_in[0];
  const float* feat = (const float*)d_in[1];
  const float* W1   = (const float*)d_in[2];
  const float* b1   = (const float*)d_in[3];
  const float* g1   = (const float*)d_in[4];
  const float* be1  = (const float*)d_in[5];
  const float* W2   = (const float*)d_in[6];
  const float* b2   = (const float*)d_in[7];
  const float* g2   = (const float*)d_in[8];
  const float* be2  = (const float*)d_in[9];
  const float* Wout = (const float*)d_in[10];
  const float* bout = (const float*)d_in[11];

  float* outp = (float*)d_out;
  float* cent = outp;                             // (B, M, 3)
  float* o    = outp + (size_t)Bn * Mn * 3;       // (B, M, 128)

  fps_kernel<<<Bn, 256, 0, stream>>>(xyz, cent);
  knn_kernel<<<Bn * Mn, 256, 0, stream>>>(xyz, cent, (int*)o);
  mlp_kernel<<<Bn * Mn / 4, 256, 0, stream>>>(xyz, feat,
                                              W1, b1, g1, be1,
                                              W2, b2, g2, be2,
                                              Wout, bout, cent, o);
}